// Round 11
// baseline (89.785 us; speedup 1.0000x reference)
//
#include <hip/hip_runtime.h>
#include <hip/hip_bf16.h>
#include <stdint.h>

// MHA B=1024,F=128,D=128,H=8,dh=16 fp32. Round 11: 1 head/block (8192 blocks).
// Q|K merged in one 32-col projection (cexp pre-folded into Wq in prep_w),
// V|R merged in the other -> proj MFMAs and LDS stores halve; Ra free on
// hb=1 lanes. Attention per-thread work halves; head-select logic deleted.
// 12 KiB LDS; __launch_bounds__(256,3) (VGPR cap ~85 -> 6 waves/SIMD).
// XCD map: batch's 8 head-blocks co-XCD + co-dispatched for X L2 reuse.

typedef __attribute__((ext_vector_type(8))) short short8;
typedef __attribute__((ext_vector_type(8))) float f32x8;
typedef __attribute__((ext_vector_type(16))) float f32x16;
typedef __attribute__((ext_vector_type(4))) unsigned int uint4v;
typedef __attribute__((ext_vector_type(2))) unsigned int uint2v;
typedef unsigned short ushort_t;
typedef unsigned int uint_t;

#define QF_OFF 0        // Qfrag[4w][1KiB]            (4 KiB)
#define KF_OFF 4096     // Kfrag[4tt][1KiB]           (4 KiB)
#define VT_OFF 8192     // Vt[16e][128f] bf16, swizzled (4 KiB)

__device__ __forceinline__ ushort_t b16(float f) {
  return __builtin_bit_cast(ushort_t, __float2bfloat16(f));
}
__device__ __forceinline__ uint_t pk2(float a, float b) {  // {lo:a, hi:b}
  return (uint_t)b16(a) | ((uint_t)b16(b) << 16);
}

// ---- prep: per-head combined tiles QK[h] (Wq*cexp || Wk) and VR[h]
// (Wv || Wr), bf16, 32x32x16 B-fragment order.
__global__ void prep_w(const float* __restrict__ Wq, const float* __restrict__ Wk,
                       const float* __restrict__ Wv, const float* __restrict__ Wr,
                       ushort_t* __restrict__ wt) {
  int i = blockIdx.x * 256 + threadIdx.x;  // 65536 total
  int u = i >> 9;          // tile*8 + kk, 128 units
  int l = (i >> 3) & 63;
  int j = i & 7;
  int tile = u >> 3, kk = u & 7;
  int h = tile >> 1, pp = tile & 1;
  int col32 = l & 31;
  int d = kk * 16 + ((l >> 5) & 1) * 8 + j;
  const float* W = (pp == 0) ? (col32 < 16 ? Wq : Wk) : (col32 < 16 ? Wv : Wr);
  float scl = (pp == 0 && col32 < 16) ? 0.12751459f : 1.0f;  // cexp into Q
  int col = 16 * h + (col32 & 15);
  wt[i] = b16(W[d * 128 + col] * scl);
}

// ---- main fused kernel -----------------------------------------------------
__global__ __launch_bounds__(256, 3) void mha11(const float* __restrict__ X,
                                                const ushort_t* __restrict__ wt,
                                                float* __restrict__ out) {
  __shared__ char lds[12288];
  const int t = threadIdx.x;
  const int w = t >> 6, l = t & 63;
  const int i = blockIdx.x;
  // batch's 8 head-blocks share XCD (i&7) and are dispatched 8 apart.
  const int b = (i & 7) * 128 + (i >> 6);
  const int h = (i >> 3) & 7;
  const int hi5 = l >> 5, q = l & 31, e = l & 15, hb = (l >> 4) & 1;

  // ---- A-fragments: wave's 32 X-rows direct from global, fp32 -> bf16 ----
  const float* xrow = X + (((size_t)b * 128) + 32 * w + q) * 128;
  short8 afr[8];
#pragma unroll
  for (int kk = 0; kk < 8; ++kk) {
    float4 a = *(const float4*)(xrow + kk * 16 + 8 * hi5);
    float4 c4 = *(const float4*)(xrow + kk * 16 + 8 * hi5 + 4);
    uint4v u = {pk2(a.x, a.y), pk2(a.z, a.w), pk2(c4.x, c4.y), pk2(c4.z, c4.w)};
    afr[kk] = __builtin_bit_cast(short8, u);
  }

  const short8* wf = (const short8*)wt;
  auto proj = [&](int pp) {
    f32x16 acc = {};
#pragma unroll
    for (int kk = 0; kk < 8; ++kk) {
      short8 bfr = wf[((h * 2 + pp) * 8 + kk) * 64 + l];
      acc = __builtin_amdgcn_mfma_f32_32x32x16_bf16(afr[kk], bfr, acc, 0, 0, 0);
    }
    return acc;
  };
  // Q (hb=0 lanes) / K (hb=1) -> fragment order + bank swizzle; e = l&15.
  auto st_qk = [&](const f32x16& d) {
    const int uxor = (e >> 3) | (hb << 1);
    char* p = lds + (hb ? KF_OFF : QF_OFF) + w * 1024 + 512 * (e >> 3) +
              (e & 7) * 2 + 64 * hi5;
#pragma unroll
    for (int r = 0; r < 16; ++r) {
      int u = (r & 3) + 8 * (r >> 2);
      *(ushort_t*)(p + 16 * (u ^ uxor)) = b16(d[r]);
    }
  };
  auto st_v = [&](const f32x16& d) {  // transposed Vt[e][f], packed 8B
#pragma unroll
    for (int q2 = 0; q2 < 4; ++q2) {
      int f0 = 32 * w + 8 * q2 + 4 * hi5;
      uint2v pk = {pk2(d[4 * q2 + 0], d[4 * q2 + 1]),
                   pk2(d[4 * q2 + 2], d[4 * q2 + 3])};
      *(uint2v*)(lds + VT_OFF + e * 256 + ((f0 * 2) ^ ((e & 7) << 4))) = pk;
    }
  };

  f32x16 Ra;  // meaningful on hb=1 lanes (R channels = cols 16-31 of VR proj)
  {
    f32x16 d = proj(0);   // Q||K
    st_qk(d);
    d = proj(1);          // V||R
    if (!hb) st_v(d);
    Ra = d;
  }
  __syncthreads();  // only barrier

  // ---- attention: one head, streaming over 32-key tiles ----
  const int swq = hi5 << 4;        // store-side uxor bit1 was hb: Q=0, K=1
  const int swk = (hi5 | 2) << 4;
  short8 qf = *(const short8*)(lds + QF_OFF + w * 1024 + ((l * 16) ^ swq));
  f32x8 eacc = {};
  f32x16 o = {};
#pragma unroll
  for (int tt = 0; tt < 4; ++tt) {
    short8 kf = *(const short8*)(lds + KF_OFF + tt * 1024 + ((l * 16) ^ swk));
    f32x16 z = {};
    f32x16 s = __builtin_amdgcn_mfma_f32_32x32x16_bf16(kf, qf, z, 0, 0, 0);
    // S pre-scaled (cexp in Wq); no max-subtraction (|s| <= ~1.1)
#pragma unroll
    for (int r = 0; r < 16; ++r) s[r] = exp2f(s[r]);
#pragma unroll
    for (int r = 0; r < 8; ++r) eacc[r] += s[r] + s[r + 8];
#pragma unroll
    for (int gg = 0; gg < 2; ++gg) {
      int rb = gg * 8, g = 2 * tt + gg;
      uint_t wl  = pk2(s[rb + 0], s[rb + 1]);
      uint_t wl2 = pk2(s[rb + 2], s[rb + 3]);
      uint_t wh  = pk2(s[rb + 4], s[rb + 5]);
      uint_t wh2 = pk2(s[rb + 6], s[rb + 7]);
      uint2v r0 = __builtin_amdgcn_permlane32_swap(wl, wh, false, false);
      uint2v r1 = __builtin_amdgcn_permlane32_swap(wl2, wh2, false, false);
      uint4v pw = {r0[0], r1[0], r0[1], r1[1]};
      short8 pa = __builtin_bit_cast(short8, pw);
      short8 vfr = *(const short8*)(lds + VT_OFF + e * 256 +
                                    ((32 * g + 16 * hi5) ^ ((e & 7) << 4)));
      o = __builtin_amdgcn_mfma_f32_32x32x16_bf16(pa, vfr, o, 0, 0, 0);
    }
  }
#pragma unroll
  for (int st = 4; st >= 1; st >>= 1)
#pragma unroll
    for (int r = 0; r < st; ++r) eacc[r] += eacc[r + st];
  float sum = eacc[0] + __shfl_xor(eacc[0], 32, 64);
  float rs = 1.0f / sum;  // lane holds rs for query q = l&31

  // ---- epilogue: normalize by rs of the QUERY ROW, add R, store (hb=1) ----
#pragma unroll
  for (int r = 0; r < 16; ++r) {
    int row = (r & 3) + 8 * (r >> 2) + 4 * hi5;
    int idx = (l & 32) | row;              // same-half lane holding that query
    float rsr = __shfl(rs, idx, 64);       // unpredicated (sources all lanes)
    float val = __builtin_fmaf(o[r], rsr, Ra[r]);
    if (hb)
      out[(((size_t)b * 128) + 32 * w + row) * 128 + 16 * h + e] = val;
  }
}

extern "C" void kernel_launch(void* const* d_in, const int* in_sizes, int n_in,
                              void* d_out, int out_size, void* d_ws, size_t ws_size,
                              hipStream_t stream) {
  const float* X  = (const float*)d_in[0];
  const float* Wq = (const float*)d_in[1];
  const float* Wk = (const float*)d_in[2];
  const float* Wv = (const float*)d_in[3];
  const float* Wr = (const float*)d_in[4];
  float* out = (float*)d_out;
  ushort_t* wt = (ushort_t*)d_ws;  // 128 KiB per-head combined weight tiles

  hipLaunchKernelGGL(prep_w, dim3(256), dim3(256), 0, stream, Wq, Wk, Wv, Wr, wt);
  hipLaunchKernelGGL(mha11, dim3(8192), dim3(256), 0, stream, X, wt, out);
}